// Round 5
// baseline (421.681 us; speedup 1.0000x reference)
//
#include <hip/hip_runtime.h>

// EvidentialGNN: 2-layer GCN. evidence = softplus(gcn2(relu(gcn1(x)))).
// Outputs concatenated: (evidence[50000,64], h[50000,256]).
// R12: agg gather loops software-pipelined (ping-pong A/B batches: batch A's
//      adds run under batch B's loads -> ~2x memory-level parallelism).
//      FETCH floor analysis: 225MB ~ 8 XCD x 25.6MB working set = structural;
//      rate 4.0/6.3 TB/s was latency-bound, not service-bound.

#define N_NODES 50000
#define IN_DIM 512
#define HID 256
#define NCLS 64

typedef unsigned short u16;
typedef unsigned int u32;
typedef __attribute__((ext_vector_type(8))) short short8;
typedef __attribute__((ext_vector_type(4))) float float4_t;

__device__ __forceinline__ float bf_lo(u32 v) {
    u32 u = v << 16; float f; __builtin_memcpy(&f, &u, 4); return f;
}
__device__ __forceinline__ float bf_hi(u32 v) {
    u32 u = v & 0xffff0000u; float f; __builtin_memcpy(&f, &u, 4); return f;
}
__device__ __forceinline__ u16 f2bf(float f) {   // RNE float->bf16
    u32 u; __builtin_memcpy(&u, &f, 4);
    return (u16)((u + 0x7fffu + ((u >> 16) & 1u)) >> 16);
}
__device__ __forceinline__ u32 pk_bf16(float lo, float hi) {  // HW RNE pack
    u32 r;
    asm("v_cvt_pk_bf16_f32 %0, %1, %2" : "=v"(r) : "v"(lo), "v"(hi));
    return r;
}
__device__ __forceinline__ void add8(float* acc, uint4 v) {
    acc[0] += bf_lo(v.x); acc[1] += bf_hi(v.x);
    acc[2] += bf_lo(v.y); acc[3] += bf_hi(v.y);
    acc[4] += bf_lo(v.z); acc[5] += bf_hi(v.z);
    acc[6] += bf_lo(v.w); acc[7] += bf_hi(v.w);
}
__device__ __forceinline__ void acc8(float* acc, uint4 v, float w) {
    acc[0] += w * bf_lo(v.x); acc[1] += w * bf_hi(v.x);
    acc[2] += w * bf_lo(v.y); acc[3] += w * bf_hi(v.y);
    acc[4] += w * bf_lo(v.z); acc[5] += w * bf_hi(v.z);
    acc[6] += w * bf_lo(v.w); acc[7] += w * bf_hi(v.w);
}
__device__ __forceinline__ void nt_store4(float* p, float a, float b, float c, float d) {
    float4_t v = {a, b, c, d};
    __builtin_nontemporal_store(v, (float4_t*)p);
}

// ---------------- graph prep ----------------
__global__ void init_kernel(int* __restrict__ cnt, int* __restrict__ cursor, int n) {
    int i = blockIdx.x * blockDim.x + threadIdx.x;
    if (i < n) { cnt[i] = 0; cursor[i] = 0; }
}

__global__ void count_kernel(const int* __restrict__ dst, int* __restrict__ cnt, int E) {
    int e = blockIdx.x * blockDim.x + threadIdx.x;
    if (e < E) atomicAdd(&cnt[dst[e]], 1);
}

// s1: per-block reduce of cnt -> blocksum; fused dinv = rsqrt(cnt+1).
__global__ __launch_bounds__(256) void s1_kernel(const int* __restrict__ cnt,
                                                 int* __restrict__ blocksum,
                                                 float* __restrict__ dinv, int n) {
    int tid = threadIdx.x;
    int i = blockIdx.x * 256 + tid;
    int c = (i < n) ? cnt[i] : 0;
    if (i < n) dinv[i] = rsqrtf((float)(c + 1));  // +1 self-loop
    __shared__ int s[256];
    s[tid] = c;
    __syncthreads();
    for (int off = 128; off > 0; off >>= 1) {
        if (tid < off) s[tid] += s[tid + off];
        __syncthreads();
    }
    if (tid == 0) blocksum[blockIdx.x] = s[0];
}

// s3 (fused s2): every block scans the <=256 block sums in LDS to get its own
// offset, then does the block-local exclusive scan -> row_ptr[0..n].
__global__ __launch_bounds__(256) void s3_kernel(const int* __restrict__ cnt,
                                                 const int* __restrict__ blocksum,
                                                 int* __restrict__ row_ptr, int n, int nb) {
    __shared__ int bs[256];
    __shared__ int s[256];
    int tid = threadIdx.x;
    int v = (tid < nb) ? blocksum[tid] : 0;
    bs[tid] = v;
    __syncthreads();
    for (int off = 1; off < 256; off <<= 1) {
        int a = (tid >= off) ? bs[tid - off] : 0;
        __syncthreads();
        bs[tid] += a;
        __syncthreads();
    }
    int boff = (blockIdx.x == 0) ? 0 : bs[blockIdx.x - 1];
    int i = blockIdx.x * 256 + tid;
    int c = (i < n) ? cnt[i] : 0;
    s[tid] = c;
    __syncthreads();
    for (int off = 1; off < 256; off <<= 1) {
        int a = (tid >= off) ? s[tid - off] : 0;
        __syncthreads();
        s[tid] += a;
        __syncthreads();
    }
    if (i <= n) row_ptr[i] = boff + s[tid] - c;
}

__global__ void fill_kernel(const int* __restrict__ src, const int* __restrict__ dst,
                            const int* __restrict__ row_ptr, int* __restrict__ cursor,
                            int* __restrict__ csr_src, int E) {
    int e = blockIdx.x * blockDim.x + threadIdx.x;
    if (e >= E) return;
    int d = dst[e];
    int pos = row_ptr[d] + atomicAdd(&cursor[d], 1);
    csr_src[pos] = src[e];
}

// ---------------- casts ----------------
// Both weight transposes in one launch.
__global__ __launch_bounds__(256) void tcast2_kernel(const float* __restrict__ W1,
                                                     u16* __restrict__ W1t,
                                                     const float* __restrict__ W2,
                                                     u16* __restrict__ W2t) {
    int idx = blockIdx.x * 256 + threadIdx.x;
    constexpr int N1 = IN_DIM * HID;
    if (idx < N1) {
        int n = idx / IN_DIM, k = idx - n * IN_DIM;
        W1t[idx] = f2bf(W1[k * HID + n]);
    } else {
        int j = idx - N1;
        if (j < HID * NCLS) {
            int n = j / HID, k = j - n * HID;
            W2t[j] = f2bf(W2[k * NCLS + n]);
        }
    }
}

// ---------------- bf16 MFMA GEMM (2-phase pipelined) ----------------
template <int BM, int BN, int K, int N, bool AF32, bool SCALE>
__global__ __launch_bounds__(256) void mfma_gemm_kernel(const void* __restrict__ Ain,
                                                        const u16* __restrict__ Bt,
                                                        u16* __restrict__ C, int M,
                                                        const float* __restrict__ rowscale) {
    constexpr int WROWS = 2, WCOLS = 2;
    constexpr int WMR = BM / WROWS;      // rows per wave
    constexpr int WNR = BN / WCOLS;      // cols per wave
    constexpr int MR = WMR / 16;         // A-frag repeat
    constexpr int NR = WNR / 16;         // B-frag repeat
    constexpr int AI = BM / 64;          // A staging iters
    constexpr int BI = BN / 64;          // B staging iters
    constexpr int LDSA = BM * 32;        // u16 per buffer
    constexpr int LDSB = BN * 32;
    constexpr int LDST = LDSA + LDSB;
    constexpr int NT = K / 32;
    static_assert(MR * 16 * WROWS == BM && NR * 16 * WCOLS == BN, "tiling");
    __shared__ u16 lds[2 * LDST];

    const int tid = threadIdx.x;
    const int wave = tid >> 6, lane = tid & 63;
    const int wm = wave / WCOLS, wn = wave % WCOLS;
    const int quad = lane >> 4, l15 = lane & 15;
    const int row0 = blockIdx.y * BM;
    const int col0 = blockIdx.x * BN;

    const float* Af = (const float*)Ain;
    const u16* Abf = (const u16*)Ain;

    int gra[AI];
#pragma unroll
    for (int i = 0; i < AI; i++) {
        int gr = row0 + ((tid + i * 256) >> 2);
        gra[i] = gr < M ? gr : M - 1;
    }

    float4 pa[AI][2];  // AF32: in-flight A fp32 for the next k-step

    auto loadA = [&](int k0) {
#pragma unroll
        for (int i = 0; i < AI; i++) {
            int c = tid + i * 256;
            const float* gp = Af + (long)gra[i] * K + k0 + (c & 3) * 8;
            pa[i][0] = ((const float4*)gp)[0];
            pa[i][1] = ((const float4*)gp)[1];
        }
    };
    auto writeA = [&](u16* buf) {
#pragma unroll
        for (int i = 0; i < AI; i++) {
            int c = tid + i * 256;
            uint4 o;
            o.x = pk_bf16(pa[i][0].x, pa[i][0].y);
            o.y = pk_bf16(pa[i][0].z, pa[i][0].w);
            o.z = pk_bf16(pa[i][1].x, pa[i][1].y);
            o.w = pk_bf16(pa[i][1].z, pa[i][1].w);
            *(uint4*)(buf + c * 8) = o;
        }
    };
    auto stageA_lds = [&](int k0, u16* buf) {
#pragma unroll
        for (int i = 0; i < AI; i++) {
            int c = tid + i * 256;
            const u16* gp = Abf + (long)gra[i] * K + k0 + (c & 3) * 8;
            __builtin_amdgcn_global_load_lds((const __attribute__((address_space(1))) u32*)gp,
                                             (__attribute__((address_space(3))) u32*)(buf + c * 8),
                                             16, 0, 0);
        }
    };
    auto stageB = [&](int k0, u16* buf) {
#pragma unroll
        for (int i = 0; i < BI; i++) {
            int c = tid + i * 256;
            int r = c >> 2;
            const u16* gp = Bt + (long)(col0 + r) * K + k0 + (c & 3) * 8;
            __builtin_amdgcn_global_load_lds((const __attribute__((address_space(1))) u32*)gp,
                                             (__attribute__((address_space(3))) u32*)(buf + c * 8),
                                             16, 0, 0);
        }
    };

    float4_t acc[MR][NR];
#pragma unroll
    for (int mi = 0; mi < MR; mi++)
#pragma unroll
        for (int ni = 0; ni < NR; ni++) {
            float4_t z = {0.f, 0.f, 0.f, 0.f};
            acc[mi][ni] = z;
        }

    if constexpr (AF32) {
        loadA(0);
        writeA(lds);
    } else {
        stageA_lds(0, lds);
    }
    stageB(0, lds + LDSA);
    __syncthreads();

    for (int t = 0; t < NT; t++) {
        u16* cur = lds + (t & 1) * LDST;
        u16* nxt = lds + ((t + 1) & 1) * LDST;
        const bool pre = (t + 1) < NT;
        if (pre) {
            if constexpr (AF32) loadA((t + 1) * 32);
            else stageA_lds((t + 1) * 32, nxt);
            stageB((t + 1) * 32, nxt + LDSA);
        }

        short8 af[MR], bfr[NR];
#pragma unroll
        for (int mi = 0; mi < MR; mi++)
            af[mi] = *(const short8*)(cur + (wm * WMR + mi * 16 + l15) * 32 + quad * 8);
#pragma unroll
        for (int ni = 0; ni < NR; ni++)
            bfr[ni] = *(const short8*)(cur + LDSA + (wn * WNR + ni * 16 + l15) * 32 + quad * 8);
#pragma unroll
        for (int mi = 0; mi < MR; mi++)
#pragma unroll
            for (int ni = 0; ni < NR; ni++)
                acc[mi][ni] = __builtin_amdgcn_mfma_f32_16x16x32_bf16(af[mi], bfr[ni],
                                                                      acc[mi][ni], 0, 0, 0);
        if (pre) {
            if constexpr (AF32) writeA(nxt);
        }
        __syncthreads();
    }

#pragma unroll
    for (int mi = 0; mi < MR; mi++) {
#pragma unroll
        for (int r = 0; r < 4; r++) {
            int row = row0 + wm * WMR + mi * 16 + quad * 4 + r;
            if (row < M) {
                float sc = 1.f;
                if constexpr (SCALE) sc = rowscale[row];
#pragma unroll
                for (int ni = 0; ni < NR; ni++) {
                    int col = col0 + wn * WNR + ni * 16 + l15;
                    C[(long)row * N + col] = f2bf(acc[mi][ni][r] * sc);
                }
            }
        }
    }
}

// ---------------- agg1: wide rows (FEAT=256), one node per wave ----------------
// Rows in t are PRE-SCALED by dinv[src]. Ping-pong pipelined: batch A's adds
// run while batch B's idx+row loads are in flight (2x MLP vs serial batches).
__global__ __launch_bounds__(256, 4) void agg_wide_kernel(const u16* __restrict__ t,
                                                          const int* __restrict__ row_ptr,
                                                          const int* __restrict__ csr_src,
                                                          const float* __restrict__ dinv,
                                                          const float* __restrict__ bias,
                                                          float* __restrict__ out_f,
                                                          u16* __restrict__ out_bf, int n) {
    constexpr int FEAT = 256;
    int node = (blockIdx.x * blockDim.x + threadIdx.x) >> 6;
    int lane = threadIdx.x & 63;
    if (node >= n) return;
    const int g = lane >> 5;       // edge group 0..1
    const int r = lane & 31;       // lane within row

    // hoisted: self row, bias, dinv (latency hidden under the edge loop)
    const float di = dinv[node];
    uint4 sv = *(const uint4*)(t + (long)node * FEAT + r * 8);
    float4 b0 = *(const float4*)(bias + r * 8);
    float4 b1 = *(const float4*)(bias + r * 8 + 4);

    float acc[8] = {};
    const int beg = row_ptr[node], end = row_ptr[node + 1];

    uint4 vA[8], vB[8];
    auto loadBatch = [&](int eb, uint4* v) {   // 8 edges for this half-wave
        int s[8];
#pragma unroll
        for (int u = 0; u < 8; u++) s[u] = csr_src[eb + u * 2 + g];
#pragma unroll
        for (int u = 0; u < 8; u++) v[u] = *(const uint4*)(t + (long)s[u] * FEAT + r * 8);
    };

    int e = beg;
    const int nb = (end - beg) >> 4;           // full 16-edge batches
    if (nb) loadBatch(e, vA);
    int i = 1;
    for (; i + 1 < nb; i += 2) {               // steady state: 32 loads in flight
        loadBatch(e + 16, vB);
#pragma unroll
        for (int u = 0; u < 8; u++) add8(acc, vA[u]);
        loadBatch(e + 32, vA);
#pragma unroll
        for (int u = 0; u < 8; u++) add8(acc, vB[u]);
        e += 32;
    }
    if (i < nb) {                              // even nb: drain pair
        loadBatch(e + 16, vB);
#pragma unroll
        for (int u = 0; u < 8; u++) add8(acc, vA[u]);
#pragma unroll
        for (int u = 0; u < 8; u++) add8(acc, vB[u]);
        e += 32;
    } else if (nb) {                           // odd nb: drain single
#pragma unroll
        for (int u = 0; u < 8; u++) add8(acc, vA[u]);
        e += 16;
    }
    for (; e + 8 <= end; e += 8) {
        int s[4]; uint4 v[4];
#pragma unroll
        for (int u = 0; u < 4; u++) s[u] = csr_src[e + u * 2 + g];
#pragma unroll
        for (int u = 0; u < 4; u++) v[u] = *(const uint4*)(t + (long)s[u] * FEAT + r * 8);
#pragma unroll
        for (int u = 0; u < 4; u++) add8(acc, v[u]);
    }
    for (; e < end; e += 2) {
        int ee = e + g;
        if (ee < end) {
            int s = csr_src[ee];
            uint4 v = *(const uint4*)(t + (long)s * FEAT + r * 8);
            add8(acc, v);
        }
    }
#pragma unroll
    for (int j = 0; j < 8; j++) acc[j] += __shfl_xor(acc[j], 32, 64);

    if (lane < 32) {
        float self[8] = {bf_lo(sv.x), bf_hi(sv.x), bf_lo(sv.y), bf_hi(sv.y),
                         bf_lo(sv.z), bf_hi(sv.z), bf_lo(sv.w), bf_hi(sv.w)};
        float bb[8] = {b0.x, b0.y, b0.z, b0.w, b1.x, b1.y, b1.z, b1.w};
        float rv[8];
#pragma unroll
        for (int j = 0; j < 8; j++)
            rv[j] = fmaxf(di * (acc[j] + self[j]) + bb[j], 0.f);  // relu
        long base = (long)node * FEAT + lane * 8;
        nt_store4(out_f + base, rv[0], rv[1], rv[2], rv[3]);
        nt_store4(out_f + base + 4, rv[4], rv[5], rv[6], rv[7]);
        uint4 o;
        o.x = pk_bf16(rv[0], rv[1]);
        o.y = pk_bf16(rv[2], rv[3]);
        o.z = pk_bf16(rv[4], rv[5]);
        o.w = pk_bf16(rv[6], rv[7]);
        *(uint4*)(out_bf + base) = o;   // re-read by GEMM2: keep cached
    }
}

// ---------------- agg2: narrow rows (FEAT=64), 8 nodes per wave ----------------
// Rows in t are PRE-SCALED by dinv[src]. Ping-pong pipelined 4-edge batches.
__global__ __launch_bounds__(256, 4) void agg_n8_kernel(const u16* __restrict__ t,
                                                        const int* __restrict__ row_ptr,
                                                        const int* __restrict__ csr_src,
                                                        const float* __restrict__ dinv,
                                                        const float* __restrict__ bias,
                                                        float* __restrict__ out_f, int n) {
    constexpr int FEAT = 64;
    const int wid = (blockIdx.x * blockDim.x + threadIdx.x) >> 6;
    const int lane = threadIdx.x & 63;
    const int g = lane >> 3;   // node group 0..7
    const int r = lane & 7;    // lane within row
    const int node = wid * 8 + g;
    const bool valid = node < n;
    const int nd = valid ? node : (n - 1);
    const int beg = row_ptr[nd];
    const int deg = valid ? (row_ptr[nd + 1] - beg) : 0;

    // hoisted: self row, bias, dinv
    const float di = dinv[nd];
    uint4 sv = *(const uint4*)(t + (long)nd * FEAT + r * 8);
    float4 b0 = *(const float4*)(bias + r * 8);
    float4 b1 = *(const float4*)(bias + r * 8 + 4);

    float acc[8] = {};
    uint4 vA[4], vB[4];
    float wA[4], wB[4];
    auto loadBatch = [&](int e0, uint4* v, float* w) {
        int s[4];
#pragma unroll
        for (int u = 0; u < 4; u++) {
            bool a = (e0 + u) < deg;
            s[u] = a ? csr_src[beg + e0 + u] : 0;
            w[u] = a ? 1.f : 0.f;
        }
#pragma unroll
        for (int u = 0; u < 4; u++) v[u] = *(const uint4*)(t + (long)s[u] * FEAT + r * 8);
    };

    // max degree within the 8-node group governs the loop count (wave-uniform)
    int e = 0;
    bool haveA = __any(0 < deg);
    if (haveA) loadBatch(0, vA, wA);
    while (haveA) {
        bool haveB = __any(e + 4 < deg);
        if (haveB) loadBatch(e + 4, vB, wB);
#pragma unroll
        for (int u = 0; u < 4; u++) acc8(acc, vA[u], wA[u]);
        e += 4;
        if (!haveB) break;
        bool haveC = __any(e + 4 < deg);
        if (haveC) loadBatch(e + 4, vA, wA);
#pragma unroll
        for (int u = 0; u < 4; u++) acc8(acc, vB[u], wB[u]);
        e += 4;
        haveA = haveC;
    }
    float self[8] = {bf_lo(sv.x), bf_hi(sv.x), bf_lo(sv.y), bf_hi(sv.y),
                     bf_lo(sv.z), bf_hi(sv.z), bf_lo(sv.w), bf_hi(sv.w)};
    float bb[8] = {b0.x, b0.y, b0.z, b0.w, b1.x, b1.y, b1.z, b1.w};
    float rv[8];
#pragma unroll
    for (int j = 0; j < 8; j++) {
        float v = di * (acc[j] + self[j]) + bb[j];
        // fast softplus: max(v,0) + ln(1+exp(-|v|)) via v_exp/v_log
        rv[j] = fmaxf(v, 0.f) + __logf(1.f + __expf(-fabsf(v)));
    }
    if (valid) {
        long base = (long)nd * FEAT + r * 8;
        nt_store4(out_f + base, rv[0], rv[1], rv[2], rv[3]);
        nt_store4(out_f + base + 4, rv[4], rv[5], rv[6], rv[7]);
    }
}

extern "C" void kernel_launch(void* const* d_in, const int* in_sizes, int n_in,
                              void* d_out, int out_size, void* d_ws, size_t ws_size,
                              hipStream_t stream) {
    const float* x  = (const float*)d_in[0];
    const int*   ei = (const int*)d_in[1];
    const float* W1 = (const float*)d_in[2];
    const float* b1 = (const float*)d_in[3];
    const float* W2 = (const float*)d_in[4];
    const float* b2 = (const float*)d_in[5];

    float* evidence = (float*)d_out;                        // [50000, 64]
    float* h        = (float*)d_out + (long)N_NODES * NCLS; // [50000, 256]

    const int E = in_sizes[1] / 2;
    const int* src = ei;
    const int* dst = ei + E;

    const int NB = (N_NODES + 255) / 256;  // 196 scan blocks

    // workspace carve-up (16B-aligned regions)
    char* w = (char*)d_ws;
    int*   cnt      = (int*)w;  w += 50048 * 4;
    int*   cursor   = (int*)w;  w += 50048 * 4;
    int*   row_ptr  = (int*)w;  w += 50064 * 4;
    float* dinv     = (float*)w; w += 50048 * 4;
    int*   blocksum = (int*)w;  w += 256 * 4;
    int*   csr_src  = (int*)w;  w += 800000 * 4;
    u16*   hbf      = (u16*)w;  w += (long)N_NODES * IN_DIM * 2;  // h bf16 (only HID used)
    u16*   w1t      = (u16*)w;  w += IN_DIM * HID * 2;
    u16*   w2t      = (u16*)w;  w += HID * NCLS * 2;
    u16*   t1bf     = (u16*)w;  w += (long)N_NODES * HID * 2;     // reused as t2_bf
    u16*   t2bf     = t1bf;

    // graph prep
    init_kernel<<<NB, 256, 0, stream>>>(cnt, cursor, N_NODES);
    count_kernel<<<(E + 255) / 256, 256, 0, stream>>>(dst, cnt, E);
    s1_kernel<<<NB, 256, 0, stream>>>(cnt, blocksum, dinv, N_NODES);
    s3_kernel<<<NB, 256, 0, stream>>>(cnt, blocksum, row_ptr, N_NODES, NB);
    fill_kernel<<<(E + 255) / 256, 256, 0, stream>>>(src, dst, row_ptr, cursor, csr_src, E);

    // weight casts (fused)
    {
        int tot = IN_DIM * HID + HID * NCLS;
        tcast2_kernel<<<(tot + 255) / 256, 256, 0, stream>>>(W1, w1t, W2, w2t);
    }

    // layer 1: t1 = dinv .* (x @ W1)  (fp32 A fused-cast, scaled epilogue);
    //          h = relu(dinv[d]*(sum t1[s] + t1[d]) + b1), also h_bf
    {
        dim3 grid(HID / 64, (N_NODES + 127) / 128);   // 4 x 391 = 1564 blocks
        mfma_gemm_kernel<128, 64, IN_DIM, HID, true, true>
            <<<grid, 256, 0, stream>>>(x, w1t, t1bf, N_NODES, dinv);
    }
    agg_wide_kernel<<<(N_NODES * 64 + 255) / 256, 256, 0, stream>>>(
        t1bf, row_ptr, csr_src, dinv, b1, h, hbf, N_NODES);

    // layer 2: t2 = dinv .* (h @ W2); evidence = softplus(dinv[d]*(sum+self) + b2)
    {
        dim3 grid(NCLS / 64, (N_NODES + 63) / 64);    // 1 x 782
        mfma_gemm_kernel<64, 64, HID, NCLS, false, true>
            <<<grid, 256, 0, stream>>>(hbf, w2t, t2bf, N_NODES, dinv);
    }
    {
        int waves = (N_NODES + 7) / 8;                 // 6250 waves
        int blocks = (waves + 3) / 4;                  // 4 waves per block
        agg_n8_kernel<<<blocks, 256, 0, stream>>>(
            t2bf, row_ptr, csr_src, dinv, b2, evidence, N_NODES);
    }
}

// Round 6
// 411.212 us; speedup vs baseline: 1.0255x; 1.0255x over previous
//
#include <hip/hip_runtime.h>

// EvidentialGNN: 2-layer GCN. evidence = softplus(gcn2(relu(gcn1(x)))).
// Outputs concatenated: (evidence[50000,64], h[50000,256]).
// R13 (= R12 minus the spill): agg ping-pong kept, but __launch_bounds__(256)
//      WITHOUT the min-waves arg. R12's (256,4) capped VGPR at 64 and spilled
//      the whole ping-pong state (+98MB WRITE = scratch). Ping-pong needs
//      ~112 VGPR -> still 16 waves/CU, no spill.

#define N_NODES 50000
#define IN_DIM 512
#define HID 256
#define NCLS 64

typedef unsigned short u16;
typedef unsigned int u32;
typedef __attribute__((ext_vector_type(8))) short short8;
typedef __attribute__((ext_vector_type(4))) float float4_t;

__device__ __forceinline__ float bf_lo(u32 v) {
    u32 u = v << 16; float f; __builtin_memcpy(&f, &u, 4); return f;
}
__device__ __forceinline__ float bf_hi(u32 v) {
    u32 u = v & 0xffff0000u; float f; __builtin_memcpy(&f, &u, 4); return f;
}
__device__ __forceinline__ u16 f2bf(float f) {   // RNE float->bf16
    u32 u; __builtin_memcpy(&u, &f, 4);
    return (u16)((u + 0x7fffu + ((u >> 16) & 1u)) >> 16);
}
__device__ __forceinline__ u32 pk_bf16(float lo, float hi) {  // HW RNE pack
    u32 r;
    asm("v_cvt_pk_bf16_f32 %0, %1, %2" : "=v"(r) : "v"(lo), "v"(hi));
    return r;
}
__device__ __forceinline__ void add8(float* acc, uint4 v) {
    acc[0] += bf_lo(v.x); acc[1] += bf_hi(v.x);
    acc[2] += bf_lo(v.y); acc[3] += bf_hi(v.y);
    acc[4] += bf_lo(v.z); acc[5] += bf_hi(v.z);
    acc[6] += bf_lo(v.w); acc[7] += bf_hi(v.w);
}
__device__ __forceinline__ void acc8(float* acc, uint4 v, float w) {
    acc[0] += w * bf_lo(v.x); acc[1] += w * bf_hi(v.x);
    acc[2] += w * bf_lo(v.y); acc[3] += w * bf_hi(v.y);
    acc[4] += w * bf_lo(v.z); acc[5] += w * bf_hi(v.z);
    acc[6] += w * bf_lo(v.w); acc[7] += w * bf_hi(v.w);
}
__device__ __forceinline__ void nt_store4(float* p, float a, float b, float c, float d) {
    float4_t v = {a, b, c, d};
    __builtin_nontemporal_store(v, (float4_t*)p);
}

// ---------------- graph prep ----------------
__global__ void init_kernel(int* __restrict__ cnt, int* __restrict__ cursor, int n) {
    int i = blockIdx.x * blockDim.x + threadIdx.x;
    if (i < n) { cnt[i] = 0; cursor[i] = 0; }
}

__global__ void count_kernel(const int* __restrict__ dst, int* __restrict__ cnt, int E) {
    int e = blockIdx.x * blockDim.x + threadIdx.x;
    if (e < E) atomicAdd(&cnt[dst[e]], 1);
}

// s1: per-block reduce of cnt -> blocksum; fused dinv = rsqrt(cnt+1).
__global__ __launch_bounds__(256) void s1_kernel(const int* __restrict__ cnt,
                                                 int* __restrict__ blocksum,
                                                 float* __restrict__ dinv, int n) {
    int tid = threadIdx.x;
    int i = blockIdx.x * 256 + tid;
    int c = (i < n) ? cnt[i] : 0;
    if (i < n) dinv[i] = rsqrtf((float)(c + 1));  // +1 self-loop
    __shared__ int s[256];
    s[tid] = c;
    __syncthreads();
    for (int off = 128; off > 0; off >>= 1) {
        if (tid < off) s[tid] += s[tid + off];
        __syncthreads();
    }
    if (tid == 0) blocksum[blockIdx.x] = s[0];
}

// s3 (fused s2): every block scans the <=256 block sums in LDS to get its own
// offset, then does the block-local exclusive scan -> row_ptr[0..n].
__global__ __launch_bounds__(256) void s3_kernel(const int* __restrict__ cnt,
                                                 const int* __restrict__ blocksum,
                                                 int* __restrict__ row_ptr, int n, int nb) {
    __shared__ int bs[256];
    __shared__ int s[256];
    int tid = threadIdx.x;
    int v = (tid < nb) ? blocksum[tid] : 0;
    bs[tid] = v;
    __syncthreads();
    for (int off = 1; off < 256; off <<= 1) {
        int a = (tid >= off) ? bs[tid - off] : 0;
        __syncthreads();
        bs[tid] += a;
        __syncthreads();
    }
    int boff = (blockIdx.x == 0) ? 0 : bs[blockIdx.x - 1];
    int i = blockIdx.x * 256 + tid;
    int c = (i < n) ? cnt[i] : 0;
    s[tid] = c;
    __syncthreads();
    for (int off = 1; off < 256; off <<= 1) {
        int a = (tid >= off) ? s[tid - off] : 0;
        __syncthreads();
        s[tid] += a;
        __syncthreads();
    }
    if (i <= n) row_ptr[i] = boff + s[tid] - c;
}

__global__ void fill_kernel(const int* __restrict__ src, const int* __restrict__ dst,
                            const int* __restrict__ row_ptr, int* __restrict__ cursor,
                            int* __restrict__ csr_src, int E) {
    int e = blockIdx.x * blockDim.x + threadIdx.x;
    if (e >= E) return;
    int d = dst[e];
    int pos = row_ptr[d] + atomicAdd(&cursor[d], 1);
    csr_src[pos] = src[e];
}

// ---------------- casts ----------------
// Both weight transposes in one launch.
__global__ __launch_bounds__(256) void tcast2_kernel(const float* __restrict__ W1,
                                                     u16* __restrict__ W1t,
                                                     const float* __restrict__ W2,
                                                     u16* __restrict__ W2t) {
    int idx = blockIdx.x * 256 + threadIdx.x;
    constexpr int N1 = IN_DIM * HID;
    if (idx < N1) {
        int n = idx / IN_DIM, k = idx - n * IN_DIM;
        W1t[idx] = f2bf(W1[k * HID + n]);
    } else {
        int j = idx - N1;
        if (j < HID * NCLS) {
            int n = j / HID, k = j - n * HID;
            W2t[j] = f2bf(W2[k * NCLS + n]);
        }
    }
}

// ---------------- bf16 MFMA GEMM (2-phase pipelined) ----------------
template <int BM, int BN, int K, int N, bool AF32, bool SCALE>
__global__ __launch_bounds__(256) void mfma_gemm_kernel(const void* __restrict__ Ain,
                                                        const u16* __restrict__ Bt,
                                                        u16* __restrict__ C, int M,
                                                        const float* __restrict__ rowscale) {
    constexpr int WROWS = 2, WCOLS = 2;
    constexpr int WMR = BM / WROWS;      // rows per wave
    constexpr int WNR = BN / WCOLS;      // cols per wave
    constexpr int MR = WMR / 16;         // A-frag repeat
    constexpr int NR = WNR / 16;         // B-frag repeat
    constexpr int AI = BM / 64;          // A staging iters
    constexpr int BI = BN / 64;          // B staging iters
    constexpr int LDSA = BM * 32;        // u16 per buffer
    constexpr int LDSB = BN * 32;
    constexpr int LDST = LDSA + LDSB;
    constexpr int NT = K / 32;
    static_assert(MR * 16 * WROWS == BM && NR * 16 * WCOLS == BN, "tiling");
    __shared__ u16 lds[2 * LDST];

    const int tid = threadIdx.x;
    const int wave = tid >> 6, lane = tid & 63;
    const int wm = wave / WCOLS, wn = wave % WCOLS;
    const int quad = lane >> 4, l15 = lane & 15;
    const int row0 = blockIdx.y * BM;
    const int col0 = blockIdx.x * BN;

    const float* Af = (const float*)Ain;
    const u16* Abf = (const u16*)Ain;

    int gra[AI];
#pragma unroll
    for (int i = 0; i < AI; i++) {
        int gr = row0 + ((tid + i * 256) >> 2);
        gra[i] = gr < M ? gr : M - 1;
    }

    float4 pa[AI][2];  // AF32: in-flight A fp32 for the next k-step

    auto loadA = [&](int k0) {
#pragma unroll
        for (int i = 0; i < AI; i++) {
            int c = tid + i * 256;
            const float* gp = Af + (long)gra[i] * K + k0 + (c & 3) * 8;
            pa[i][0] = ((const float4*)gp)[0];
            pa[i][1] = ((const float4*)gp)[1];
        }
    };
    auto writeA = [&](u16* buf) {
#pragma unroll
        for (int i = 0; i < AI; i++) {
            int c = tid + i * 256;
            uint4 o;
            o.x = pk_bf16(pa[i][0].x, pa[i][0].y);
            o.y = pk_bf16(pa[i][0].z, pa[i][0].w);
            o.z = pk_bf16(pa[i][1].x, pa[i][1].y);
            o.w = pk_bf16(pa[i][1].z, pa[i][1].w);
            *(uint4*)(buf + c * 8) = o;
        }
    };
    auto stageA_lds = [&](int k0, u16* buf) {
#pragma unroll
        for (int i = 0; i < AI; i++) {
            int c = tid + i * 256;
            const u16* gp = Abf + (long)gra[i] * K + k0 + (c & 3) * 8;
            __builtin_amdgcn_global_load_lds((const __attribute__((address_space(1))) u32*)gp,
                                             (__attribute__((address_space(3))) u32*)(buf + c * 8),
                                             16, 0, 0);
        }
    };
    auto stageB = [&](int k0, u16* buf) {
#pragma unroll
        for (int i = 0; i < BI; i++) {
            int c = tid + i * 256;
            int r = c >> 2;
            const u16* gp = Bt + (long)(col0 + r) * K + k0 + (c & 3) * 8;
            __builtin_amdgcn_global_load_lds((const __attribute__((address_space(1))) u32*)gp,
                                             (__attribute__((address_space(3))) u32*)(buf + c * 8),
                                             16, 0, 0);
        }
    };

    float4_t acc[MR][NR];
#pragma unroll
    for (int mi = 0; mi < MR; mi++)
#pragma unroll
        for (int ni = 0; ni < NR; ni++) {
            float4_t z = {0.f, 0.f, 0.f, 0.f};
            acc[mi][ni] = z;
        }

    if constexpr (AF32) {
        loadA(0);
        writeA(lds);
    } else {
        stageA_lds(0, lds);
    }
    stageB(0, lds + LDSA);
    __syncthreads();

    for (int t = 0; t < NT; t++) {
        u16* cur = lds + (t & 1) * LDST;
        u16* nxt = lds + ((t + 1) & 1) * LDST;
        const bool pre = (t + 1) < NT;
        if (pre) {
            if constexpr (AF32) loadA((t + 1) * 32);
            else stageA_lds((t + 1) * 32, nxt);
            stageB((t + 1) * 32, nxt + LDSA);
        }

        short8 af[MR], bfr[NR];
#pragma unroll
        for (int mi = 0; mi < MR; mi++)
            af[mi] = *(const short8*)(cur + (wm * WMR + mi * 16 + l15) * 32 + quad * 8);
#pragma unroll
        for (int ni = 0; ni < NR; ni++)
            bfr[ni] = *(const short8*)(cur + LDSA + (wn * WNR + ni * 16 + l15) * 32 + quad * 8);
#pragma unroll
        for (int mi = 0; mi < MR; mi++)
#pragma unroll
            for (int ni = 0; ni < NR; ni++)
                acc[mi][ni] = __builtin_amdgcn_mfma_f32_16x16x32_bf16(af[mi], bfr[ni],
                                                                      acc[mi][ni], 0, 0, 0);
        if (pre) {
            if constexpr (AF32) writeA(nxt);
        }
        __syncthreads();
    }

#pragma unroll
    for (int mi = 0; mi < MR; mi++) {
#pragma unroll
        for (int r = 0; r < 4; r++) {
            int row = row0 + wm * WMR + mi * 16 + quad * 4 + r;
            if (row < M) {
                float sc = 1.f;
                if constexpr (SCALE) sc = rowscale[row];
#pragma unroll
                for (int ni = 0; ni < NR; ni++) {
                    int col = col0 + wn * WNR + ni * 16 + l15;
                    C[(long)row * N + col] = f2bf(acc[mi][ni][r] * sc);
                }
            }
        }
    }
}

// ---------------- agg1: wide rows (FEAT=256), one node per wave ----------------
// Rows in t are PRE-SCALED by dinv[src]. Ping-pong pipelined: batch A's adds
// run while batch B's idx+row loads are in flight (2x MLP vs serial batches).
// NOTE: plain __launch_bounds__(256) — a min-waves arg here caps VGPR and
// spills the ping-pong state (R12: +98MB scratch writes).
__global__ __launch_bounds__(256) void agg_wide_kernel(const u16* __restrict__ t,
                                                       const int* __restrict__ row_ptr,
                                                       const int* __restrict__ csr_src,
                                                       const float* __restrict__ dinv,
                                                       const float* __restrict__ bias,
                                                       float* __restrict__ out_f,
                                                       u16* __restrict__ out_bf, int n) {
    constexpr int FEAT = 256;
    int node = (blockIdx.x * blockDim.x + threadIdx.x) >> 6;
    int lane = threadIdx.x & 63;
    if (node >= n) return;
    const int g = lane >> 5;       // edge group 0..1
    const int r = lane & 31;       // lane within row

    // hoisted: self row, bias, dinv (latency hidden under the edge loop)
    const float di = dinv[node];
    uint4 sv = *(const uint4*)(t + (long)node * FEAT + r * 8);
    float4 b0 = *(const float4*)(bias + r * 8);
    float4 b1 = *(const float4*)(bias + r * 8 + 4);

    float acc[8] = {};
    const int beg = row_ptr[node], end = row_ptr[node + 1];

    uint4 vA[8], vB[8];
    auto loadBatch = [&](int eb, uint4* v) {   // 8 edges for this half-wave
        int s[8];
#pragma unroll
        for (int u = 0; u < 8; u++) s[u] = csr_src[eb + u * 2 + g];
#pragma unroll
        for (int u = 0; u < 8; u++) v[u] = *(const uint4*)(t + (long)s[u] * FEAT + r * 8);
    };

    int e = beg;
    const int nb = (end - beg) >> 4;           // full 16-edge batches
    if (nb) loadBatch(e, vA);
    int i = 1;
    for (; i + 1 < nb; i += 2) {               // steady state: 32 loads in flight
        loadBatch(e + 16, vB);
#pragma unroll
        for (int u = 0; u < 8; u++) add8(acc, vA[u]);
        loadBatch(e + 32, vA);
#pragma unroll
        for (int u = 0; u < 8; u++) add8(acc, vB[u]);
        e += 32;
    }
    if (i < nb) {                              // even nb: drain pair
        loadBatch(e + 16, vB);
#pragma unroll
        for (int u = 0; u < 8; u++) add8(acc, vA[u]);
#pragma unroll
        for (int u = 0; u < 8; u++) add8(acc, vB[u]);
        e += 32;
    } else if (nb) {                           // odd nb: drain single
#pragma unroll
        for (int u = 0; u < 8; u++) add8(acc, vA[u]);
        e += 16;
    }
    for (; e + 8 <= end; e += 8) {
        int s[4]; uint4 v[4];
#pragma unroll
        for (int u = 0; u < 4; u++) s[u] = csr_src[e + u * 2 + g];
#pragma unroll
        for (int u = 0; u < 4; u++) v[u] = *(const uint4*)(t + (long)s[u] * FEAT + r * 8);
#pragma unroll
        for (int u = 0; u < 4; u++) add8(acc, v[u]);
    }
    for (; e < end; e += 2) {
        int ee = e + g;
        if (ee < end) {
            int s = csr_src[ee];
            uint4 v = *(const uint4*)(t + (long)s * FEAT + r * 8);
            add8(acc, v);
        }
    }
#pragma unroll
    for (int j = 0; j < 8; j++) acc[j] += __shfl_xor(acc[j], 32, 64);

    if (lane < 32) {
        float self[8] = {bf_lo(sv.x), bf_hi(sv.x), bf_lo(sv.y), bf_hi(sv.y),
                         bf_lo(sv.z), bf_hi(sv.z), bf_lo(sv.w), bf_hi(sv.w)};
        float bb[8] = {b0.x, b0.y, b0.z, b0.w, b1.x, b1.y, b1.z, b1.w};
        float rv[8];
#pragma unroll
        for (int j = 0; j < 8; j++)
            rv[j] = fmaxf(di * (acc[j] + self[j]) + bb[j], 0.f);  // relu
        long base = (long)node * FEAT + lane * 8;
        nt_store4(out_f + base, rv[0], rv[1], rv[2], rv[3]);
        nt_store4(out_f + base + 4, rv[4], rv[5], rv[6], rv[7]);
        uint4 o;
        o.x = pk_bf16(rv[0], rv[1]);
        o.y = pk_bf16(rv[2], rv[3]);
        o.z = pk_bf16(rv[4], rv[5]);
        o.w = pk_bf16(rv[6], rv[7]);
        *(uint4*)(out_bf + base) = o;   // re-read by GEMM2: keep cached
    }
}

// ---------------- agg2: narrow rows (FEAT=64), 8 nodes per wave ----------------
// Rows in t are PRE-SCALED by dinv[src]. Ping-pong pipelined 4-edge batches.
__global__ __launch_bounds__(256) void agg_n8_kernel(const u16* __restrict__ t,
                                                     const int* __restrict__ row_ptr,
                                                     const int* __restrict__ csr_src,
                                                     const float* __restrict__ dinv,
                                                     const float* __restrict__ bias,
                                                     float* __restrict__ out_f, int n) {
    constexpr int FEAT = 64;
    const int wid = (blockIdx.x * blockDim.x + threadIdx.x) >> 6;
    const int lane = threadIdx.x & 63;
    const int g = lane >> 3;   // node group 0..7
    const int r = lane & 7;    // lane within row
    const int node = wid * 8 + g;
    const bool valid = node < n;
    const int nd = valid ? node : (n - 1);
    const int beg = row_ptr[nd];
    const int deg = valid ? (row_ptr[nd + 1] - beg) : 0;

    // hoisted: self row, bias, dinv
    const float di = dinv[nd];
    uint4 sv = *(const uint4*)(t + (long)nd * FEAT + r * 8);
    float4 b0 = *(const float4*)(bias + r * 8);
    float4 b1 = *(const float4*)(bias + r * 8 + 4);

    float acc[8] = {};
    uint4 vA[4], vB[4];
    float wA[4], wB[4];
    auto loadBatch = [&](int e0, uint4* v, float* w) {
        int s[4];
#pragma unroll
        for (int u = 0; u < 4; u++) {
            bool a = (e0 + u) < deg;
            s[u] = a ? csr_src[beg + e0 + u] : 0;
            w[u] = a ? 1.f : 0.f;
        }
#pragma unroll
        for (int u = 0; u < 4; u++) v[u] = *(const uint4*)(t + (long)s[u] * FEAT + r * 8);
    };

    // max degree within the 8-node group governs the loop count (wave-uniform)
    int e = 0;
    bool haveA = __any(0 < deg);
    if (haveA) loadBatch(0, vA, wA);
    while (haveA) {
        bool haveB = __any(e + 4 < deg);
        if (haveB) loadBatch(e + 4, vB, wB);
#pragma unroll
        for (int u = 0; u < 4; u++) acc8(acc, vA[u], wA[u]);
        e += 4;
        if (!haveB) break;
        bool haveC = __any(e + 4 < deg);
        if (haveC) loadBatch(e + 4, vA, wA);
#pragma unroll
        for (int u = 0; u < 4; u++) acc8(acc, vB[u], wB[u]);
        e += 4;
        haveA = haveC;
    }
    float self[8] = {bf_lo(sv.x), bf_hi(sv.x), bf_lo(sv.y), bf_hi(sv.y),
                     bf_lo(sv.z), bf_hi(sv.z), bf_lo(sv.w), bf_hi(sv.w)};
    float bb[8] = {b0.x, b0.y, b0.z, b0.w, b1.x, b1.y, b1.z, b1.w};
    float rv[8];
#pragma unroll
    for (int j = 0; j < 8; j++) {
        float v = di * (acc[j] + self[j]) + bb[j];
        // fast softplus: max(v,0) + ln(1+exp(-|v|)) via v_exp/v_log
        rv[j] = fmaxf(v, 0.f) + __logf(1.f + __expf(-fabsf(v)));
    }
    if (valid) {
        long base = (long)nd * FEAT + r * 8;
        nt_store4(out_f + base, rv[0], rv[1], rv[2], rv[3]);
        nt_store4(out_f + base + 4, rv[4], rv[5], rv[6], rv[7]);
    }
}

extern "C" void kernel_launch(void* const* d_in, const int* in_sizes, int n_in,
                              void* d_out, int out_size, void* d_ws, size_t ws_size,
                              hipStream_t stream) {
    const float* x  = (const float*)d_in[0];
    const int*   ei = (const int*)d_in[1];
    const float* W1 = (const float*)d_in[2];
    const float* b1 = (const float*)d_in[3];
    const float* W2 = (const float*)d_in[4];
    const float* b2 = (const float*)d_in[5];

    float* evidence = (float*)d_out;                        // [50000, 64]
    float* h        = (float*)d_out + (long)N_NODES * NCLS; // [50000, 256]

    const int E = in_sizes[1] / 2;
    const int* src = ei;
    const int* dst = ei + E;

    const int NB = (N_NODES + 255) / 256;  // 196 scan blocks

    // workspace carve-up (16B-aligned regions)
    char* w = (char*)d_ws;
    int*   cnt      = (int*)w;  w += 50048 * 4;
    int*   cursor   = (int*)w;  w += 50048 * 4;
    int*   row_ptr  = (int*)w;  w += 50064 * 4;
    float* dinv     = (float*)w; w += 50048 * 4;
    int*   blocksum = (int*)w;  w += 256 * 4;
    int*   csr_src  = (int*)w;  w += 800000 * 4;
    u16*   hbf      = (u16*)w;  w += (long)N_NODES * IN_DIM * 2;  // h bf16 (only HID used)
    u16*   w1t      = (u16*)w;  w += IN_DIM * HID * 2;
    u16*   w2t      = (u16*)w;  w += HID * NCLS * 2;
    u16*   t1bf     = (u16*)w;  w += (long)N_NODES * HID * 2;     // reused as t2_bf
    u16*   t2bf     = t1bf;

    // graph prep
    init_kernel<<<NB, 256, 0, stream>>>(cnt, cursor, N_NODES);
    count_kernel<<<(E + 255) / 256, 256, 0, stream>>>(dst, cnt, E);
    s1_kernel<<<NB, 256, 0, stream>>>(cnt, blocksum, dinv, N_NODES);
    s3_kernel<<<NB, 256, 0, stream>>>(cnt, blocksum, row_ptr, N_NODES, NB);
    fill_kernel<<<(E + 255) / 256, 256, 0, stream>>>(src, dst, row_ptr, cursor, csr_src, E);

    // weight casts (fused)
    {
        int tot = IN_DIM * HID + HID * NCLS;
        tcast2_kernel<<<(tot + 255) / 256, 256, 0, stream>>>(W1, w1t, W2, w2t);
    }

    // layer 1: t1 = dinv .* (x @ W1)  (fp32 A fused-cast, scaled epilogue);
    //          h = relu(dinv[d]*(sum t1[s] + t1[d]) + b1), also h_bf
    {
        dim3 grid(HID / 64, (N_NODES + 127) / 128);   // 4 x 391 = 1564 blocks
        mfma_gemm_kernel<128, 64, IN_DIM, HID, true, true>
            <<<grid, 256, 0, stream>>>(x, w1t, t1bf, N_NODES, dinv);
    }
    agg_wide_kernel<<<(N_NODES * 64 + 255) / 256, 256, 0, stream>>>(
        t1bf, row_ptr, csr_src, dinv, b1, h, hbf, N_NODES);

    // layer 2: t2 = dinv .* (h @ W2); evidence = softplus(dinv[d]*(sum+self) + b2)
    {
        dim3 grid(NCLS / 64, (N_NODES + 63) / 64);    // 1 x 782
        mfma_gemm_kernel<64, 64, HID, NCLS, false, true>
            <<<grid, 256, 0, stream>>>(hbf, w2t, t2bf, N_NODES, dinv);
    }
    {
        int waves = (N_NODES + 7) / 8;                 // 6250 waves
        int blocks = (waves + 3) / 4;                  // 4 waves per block
        agg_n8_kernel<<<blocks, 256, 0, stream>>>(
            t2bf, row_ptr, csr_src, dinv, b2, evidence, N_NODES);
    }
}

// Round 7
// 396.644 us; speedup vs baseline: 1.0631x; 1.0367x over previous
//
#include <hip/hip_runtime.h>

// EvidentialGNN: 2-layer GCN. evidence = softplus(gcn2(relu(gcn1(x)))).
// Outputs concatenated: (evidence[50000,64], h[50000,256]).
// R14: aggs reverted to R11 serial-batch form (R12/R13 proved per-wave
//      ping-pong trades occupancy for ILP at a net loss: 48->68 VGPR crossed
//      the 64-VGPR tier, 43->25% occupancy, 77->85us). GEMM1 AF32 staging now
//      2-deep prefetch (loadA(t+2) issued at iter t into named paA/paB;
//      writeA consumes data a full iteration old -> vmcnt wait ~free).

#define N_NODES 50000
#define IN_DIM 512
#define HID 256
#define NCLS 64

typedef unsigned short u16;
typedef unsigned int u32;
typedef __attribute__((ext_vector_type(8))) short short8;
typedef __attribute__((ext_vector_type(4))) float float4_t;

__device__ __forceinline__ float bf_lo(u32 v) {
    u32 u = v << 16; float f; __builtin_memcpy(&f, &u, 4); return f;
}
__device__ __forceinline__ float bf_hi(u32 v) {
    u32 u = v & 0xffff0000u; float f; __builtin_memcpy(&f, &u, 4); return f;
}
__device__ __forceinline__ u16 f2bf(float f) {   // RNE float->bf16
    u32 u; __builtin_memcpy(&u, &f, 4);
    return (u16)((u + 0x7fffu + ((u >> 16) & 1u)) >> 16);
}
__device__ __forceinline__ u32 pk_bf16(float lo, float hi) {  // HW RNE pack
    u32 r;
    asm("v_cvt_pk_bf16_f32 %0, %1, %2" : "=v"(r) : "v"(lo), "v"(hi));
    return r;
}
__device__ __forceinline__ void add8(float* acc, uint4 v) {
    acc[0] += bf_lo(v.x); acc[1] += bf_hi(v.x);
    acc[2] += bf_lo(v.y); acc[3] += bf_hi(v.y);
    acc[4] += bf_lo(v.z); acc[5] += bf_hi(v.z);
    acc[6] += bf_lo(v.w); acc[7] += bf_hi(v.w);
}
__device__ __forceinline__ void acc8(float* acc, uint4 v, float w) {
    acc[0] += w * bf_lo(v.x); acc[1] += w * bf_hi(v.x);
    acc[2] += w * bf_lo(v.y); acc[3] += w * bf_hi(v.y);
    acc[4] += w * bf_lo(v.z); acc[5] += w * bf_hi(v.z);
    acc[6] += w * bf_lo(v.w); acc[7] += w * bf_hi(v.w);
}
__device__ __forceinline__ void nt_store4(float* p, float a, float b, float c, float d) {
    float4_t v = {a, b, c, d};
    __builtin_nontemporal_store(v, (float4_t*)p);
}

// ---------------- graph prep ----------------
__global__ void init_kernel(int* __restrict__ cnt, int* __restrict__ cursor, int n) {
    int i = blockIdx.x * blockDim.x + threadIdx.x;
    if (i < n) { cnt[i] = 0; cursor[i] = 0; }
}

__global__ void count_kernel(const int* __restrict__ dst, int* __restrict__ cnt, int E) {
    int e = blockIdx.x * blockDim.x + threadIdx.x;
    if (e < E) atomicAdd(&cnt[dst[e]], 1);
}

// s1: per-block reduce of cnt -> blocksum; fused dinv = rsqrt(cnt+1).
__global__ __launch_bounds__(256) void s1_kernel(const int* __restrict__ cnt,
                                                 int* __restrict__ blocksum,
                                                 float* __restrict__ dinv, int n) {
    int tid = threadIdx.x;
    int i = blockIdx.x * 256 + tid;
    int c = (i < n) ? cnt[i] : 0;
    if (i < n) dinv[i] = rsqrtf((float)(c + 1));  // +1 self-loop
    __shared__ int s[256];
    s[tid] = c;
    __syncthreads();
    for (int off = 128; off > 0; off >>= 1) {
        if (tid < off) s[tid] += s[tid + off];
        __syncthreads();
    }
    if (tid == 0) blocksum[blockIdx.x] = s[0];
}

// s3 (fused s2): every block scans the <=256 block sums in LDS to get its own
// offset, then does the block-local exclusive scan -> row_ptr[0..n].
__global__ __launch_bounds__(256) void s3_kernel(const int* __restrict__ cnt,
                                                 const int* __restrict__ blocksum,
                                                 int* __restrict__ row_ptr, int n, int nb) {
    __shared__ int bs[256];
    __shared__ int s[256];
    int tid = threadIdx.x;
    int v = (tid < nb) ? blocksum[tid] : 0;
    bs[tid] = v;
    __syncthreads();
    for (int off = 1; off < 256; off <<= 1) {
        int a = (tid >= off) ? bs[tid - off] : 0;
        __syncthreads();
        bs[tid] += a;
        __syncthreads();
    }
    int boff = (blockIdx.x == 0) ? 0 : bs[blockIdx.x - 1];
    int i = blockIdx.x * 256 + tid;
    int c = (i < n) ? cnt[i] : 0;
    s[tid] = c;
    __syncthreads();
    for (int off = 1; off < 256; off <<= 1) {
        int a = (tid >= off) ? s[tid - off] : 0;
        __syncthreads();
        s[tid] += a;
        __syncthreads();
    }
    if (i <= n) row_ptr[i] = boff + s[tid] - c;
}

__global__ void fill_kernel(const int* __restrict__ src, const int* __restrict__ dst,
                            const int* __restrict__ row_ptr, int* __restrict__ cursor,
                            int* __restrict__ csr_src, int E) {
    int e = blockIdx.x * blockDim.x + threadIdx.x;
    if (e >= E) return;
    int d = dst[e];
    int pos = row_ptr[d] + atomicAdd(&cursor[d], 1);
    csr_src[pos] = src[e];
}

// ---------------- casts ----------------
// Both weight transposes in one launch.
__global__ __launch_bounds__(256) void tcast2_kernel(const float* __restrict__ W1,
                                                     u16* __restrict__ W1t,
                                                     const float* __restrict__ W2,
                                                     u16* __restrict__ W2t) {
    int idx = blockIdx.x * 256 + threadIdx.x;
    constexpr int N1 = IN_DIM * HID;
    if (idx < N1) {
        int n = idx / IN_DIM, k = idx - n * IN_DIM;
        W1t[idx] = f2bf(W1[k * HID + n]);
    } else {
        int j = idx - N1;
        if (j < HID * NCLS) {
            int n = j / HID, k = j - n * HID;
            W2t[j] = f2bf(W2[k * NCLS + n]);
        }
    }
}

// ---------------- bf16 MFMA GEMM (pipelined) ----------------
// C[M,N] = A[M,K] @ Bt[N,K]^T, fp32 accumulate, bf16 out.
// AF32: A fp32, staged via regs (2-deep prefetch: loadA(t+2) in flight while
// writeA(t+1) converts data issued a full iteration earlier -> wait ~free).
// SCALE: epilogue multiplies each output row by rowscale[row].
template <int BM, int BN, int K, int N, bool AF32, bool SCALE>
__global__ __launch_bounds__(256) void mfma_gemm_kernel(const void* __restrict__ Ain,
                                                        const u16* __restrict__ Bt,
                                                        u16* __restrict__ C, int M,
                                                        const float* __restrict__ rowscale) {
    constexpr int WROWS = 2, WCOLS = 2;
    constexpr int WMR = BM / WROWS;      // rows per wave
    constexpr int WNR = BN / WCOLS;      // cols per wave
    constexpr int MR = WMR / 16;         // A-frag repeat
    constexpr int NR = WNR / 16;         // B-frag repeat
    constexpr int AI = BM / 64;          // A staging iters
    constexpr int BI = BN / 64;          // B staging iters
    constexpr int LDSA = BM * 32;        // u16 per buffer
    constexpr int LDSB = BN * 32;
    constexpr int LDST = LDSA + LDSB;
    constexpr int NT = K / 32;
    static_assert(MR * 16 * WROWS == BM && NR * 16 * WCOLS == BN, "tiling");
    static_assert(!AF32 || (NT % 2 == 0), "2-deep prefetch needs even NT");
    __shared__ u16 lds[2 * LDST];

    const int tid = threadIdx.x;
    const int wave = tid >> 6, lane = tid & 63;
    const int wm = wave / WCOLS, wn = wave % WCOLS;
    const int quad = lane >> 4, l15 = lane & 15;
    const int row0 = blockIdx.y * BM;
    const int col0 = blockIdx.x * BN;

    const float* Af = (const float*)Ain;
    const u16* Abf = (const u16*)Ain;

    int gra[AI];
#pragma unroll
    for (int i = 0; i < AI; i++) {
        int gr = row0 + ((tid + i * 256) >> 2);
        gra[i] = gr < M ? gr : M - 1;
    }

    auto loadA = [&](int k0, float4 (&pa)[AI][2]) {
#pragma unroll
        for (int i = 0; i < AI; i++) {
            int c = tid + i * 256;
            const float* gp = Af + (long)gra[i] * K + k0 + (c & 3) * 8;
            pa[i][0] = ((const float4*)gp)[0];
            pa[i][1] = ((const float4*)gp)[1];
        }
    };
    auto writeA = [&](u16* buf, float4 (&pa)[AI][2]) {
#pragma unroll
        for (int i = 0; i < AI; i++) {
            int c = tid + i * 256;
            uint4 o;
            o.x = pk_bf16(pa[i][0].x, pa[i][0].y);
            o.y = pk_bf16(pa[i][0].z, pa[i][0].w);
            o.z = pk_bf16(pa[i][1].x, pa[i][1].y);
            o.w = pk_bf16(pa[i][1].z, pa[i][1].w);
            *(uint4*)(buf + c * 8) = o;
        }
    };
    auto stageA_lds = [&](int k0, u16* buf) {
#pragma unroll
        for (int i = 0; i < AI; i++) {
            int c = tid + i * 256;
            const u16* gp = Abf + (long)gra[i] * K + k0 + (c & 3) * 8;
            __builtin_amdgcn_global_load_lds((const __attribute__((address_space(1))) u32*)gp,
                                             (__attribute__((address_space(3))) u32*)(buf + c * 8),
                                             16, 0, 0);
        }
    };
    auto stageB = [&](int k0, u16* buf) {
#pragma unroll
        for (int i = 0; i < BI; i++) {
            int c = tid + i * 256;
            int r = c >> 2;
            const u16* gp = Bt + (long)(col0 + r) * K + k0 + (c & 3) * 8;
            __builtin_amdgcn_global_load_lds((const __attribute__((address_space(1))) u32*)gp,
                                             (__attribute__((address_space(3))) u32*)(buf + c * 8),
                                             16, 0, 0);
        }
    };

    float4_t acc[MR][NR];
#pragma unroll
    for (int mi = 0; mi < MR; mi++)
#pragma unroll
        for (int ni = 0; ni < NR; ni++) {
            float4_t z = {0.f, 0.f, 0.f, 0.f};
            acc[mi][ni] = z;
        }

    // per-iteration compute on buffer `cur`
    auto compute = [&](const u16* cur) {
        short8 af[MR], bfr[NR];
#pragma unroll
        for (int mi = 0; mi < MR; mi++)
            af[mi] = *(const short8*)(cur + (wm * WMR + mi * 16 + l15) * 32 + quad * 8);
#pragma unroll
        for (int ni = 0; ni < NR; ni++)
            bfr[ni] = *(const short8*)(cur + LDSA + (wn * WNR + ni * 16 + l15) * 32 + quad * 8);
#pragma unroll
        for (int mi = 0; mi < MR; mi++)
#pragma unroll
            for (int ni = 0; ni < NR; ni++)
                acc[mi][ni] = __builtin_amdgcn_mfma_f32_16x16x32_bf16(af[mi], bfr[ni],
                                                                      acc[mi][ni], 0, 0, 0);
    };

    if constexpr (AF32) {
        float4 paA[AI][2], paB[AI][2];   // named double prefetch buffers
        loadA(0, paA);
        writeA(lds, paA);                // tile 0 -> buf0
        stageB(0, lds + LDSA);
        loadA(32, paA);                  // tile 1 in flight
        __syncthreads();

        // unroll-by-2 so paA/paB stay statically named (no runtime indexing)
        for (int t = 0; t < NT; t += 2) {
            // even step: cur=buf[t&1]=buf0-parity; paA holds tile t+1
            {
                u16* cur = lds + (t & 1) * LDST;
                u16* nxt = lds + ((t + 1) & 1) * LDST;
                if (t + 2 < NT) loadA((t + 2) * 32, paB);
                if (t + 1 < NT) stageB((t + 1) * 32, nxt + LDSA);
                compute(cur);
                if (t + 1 < NT) writeA(nxt, paA);  // data issued 1 full iter ago
                __syncthreads();
            }
            // odd step: paB holds tile t+2
            {
                int t1 = t + 1;
                if (t1 < NT) {
                    u16* cur = lds + (t1 & 1) * LDST;
                    u16* nxt = lds + ((t1 + 1) & 1) * LDST;
                    if (t1 + 2 < NT) loadA((t1 + 2) * 32, paA);
                    if (t1 + 1 < NT) stageB((t1 + 1) * 32, nxt + LDSA);
                    compute(cur);
                    if (t1 + 1 < NT) writeA(nxt, paB);
                    __syncthreads();
                }
            }
        }
    } else {
        stageA_lds(0, lds);
        stageB(0, lds + LDSA);
        __syncthreads();
        for (int t = 0; t < NT; t++) {
            u16* cur = lds + (t & 1) * LDST;
            u16* nxt = lds + ((t + 1) & 1) * LDST;
            const bool pre = (t + 1) < NT;
            if (pre) {
                stageA_lds((t + 1) * 32, nxt);
                stageB((t + 1) * 32, nxt + LDSA);
            }
            compute(cur);
            __syncthreads();
        }
    }

#pragma unroll
    for (int mi = 0; mi < MR; mi++) {
#pragma unroll
        for (int r = 0; r < 4; r++) {
            int row = row0 + wm * WMR + mi * 16 + quad * 4 + r;
            if (row < M) {
                float sc = 1.f;
                if constexpr (SCALE) sc = rowscale[row];
#pragma unroll
                for (int ni = 0; ni < NR; ni++) {
                    int col = col0 + wn * WNR + ni * 16 + l15;
                    C[(long)row * N + col] = f2bf(acc[mi][ni][r] * sc);
                }
            }
        }
    }
}

// ---------------- agg1: wide rows (FEAT=256), one node per wave ----------------
// Rows in t are PRE-SCALED by dinv[src] (GEMM epilogue): pure row-sum.
// R11 serial-batch form (48 VGPR, 8 waves/SIMD tier) — per-wave ping-pong
// regressed occupancy (R12/R13).
__global__ __launch_bounds__(256) void agg_wide_kernel(const u16* __restrict__ t,
                                                       const int* __restrict__ row_ptr,
                                                       const int* __restrict__ csr_src,
                                                       const float* __restrict__ dinv,
                                                       const float* __restrict__ bias,
                                                       float* __restrict__ out_f,
                                                       u16* __restrict__ out_bf, int n) {
    constexpr int FEAT = 256;
    int node = (blockIdx.x * blockDim.x + threadIdx.x) >> 6;
    int lane = threadIdx.x & 63;
    if (node >= n) return;
    const int g = lane >> 5;       // edge group 0..1
    const int r = lane & 31;       // lane within row

    // hoisted: self row, bias, dinv (latency hidden under the edge loop)
    const float di = dinv[node];
    uint4 sv = *(const uint4*)(t + (long)node * FEAT + r * 8);
    float4 b0 = *(const float4*)(bias + r * 8);
    float4 b1 = *(const float4*)(bias + r * 8 + 4);

    float acc[8] = {};
    const int beg = row_ptr[node], end = row_ptr[node + 1];
    int e = beg;
    for (; e + 16 <= end; e += 16) {   // 8 edges per group, 16 chains in flight
        int s[8]; uint4 v[8];
#pragma unroll
        for (int u = 0; u < 8; u++) s[u] = csr_src[e + u * 2 + g];
#pragma unroll
        for (int u = 0; u < 8; u++) v[u] = *(const uint4*)(t + (long)s[u] * FEAT + r * 8);
#pragma unroll
        for (int u = 0; u < 8; u++) add8(acc, v[u]);
    }
    for (; e + 8 <= end; e += 8) {
        int s[4]; uint4 v[4];
#pragma unroll
        for (int u = 0; u < 4; u++) s[u] = csr_src[e + u * 2 + g];
#pragma unroll
        for (int u = 0; u < 4; u++) v[u] = *(const uint4*)(t + (long)s[u] * FEAT + r * 8);
#pragma unroll
        for (int u = 0; u < 4; u++) add8(acc, v[u]);
    }
    for (; e < end; e += 2) {
        int ee = e + g;
        if (ee < end) {
            int s = csr_src[ee];
            uint4 v = *(const uint4*)(t + (long)s * FEAT + r * 8);
            add8(acc, v);
        }
    }
#pragma unroll
    for (int j = 0; j < 8; j++) acc[j] += __shfl_xor(acc[j], 32, 64);

    if (lane < 32) {
        float self[8] = {bf_lo(sv.x), bf_hi(sv.x), bf_lo(sv.y), bf_hi(sv.y),
                         bf_lo(sv.z), bf_hi(sv.z), bf_lo(sv.w), bf_hi(sv.w)};
        float bb[8] = {b0.x, b0.y, b0.z, b0.w, b1.x, b1.y, b1.z, b1.w};
        float rv[8];
#pragma unroll
        for (int j = 0; j < 8; j++)
            rv[j] = fmaxf(di * (acc[j] + self[j]) + bb[j], 0.f);  // relu
        long base = (long)node * FEAT + lane * 8;
        nt_store4(out_f + base, rv[0], rv[1], rv[2], rv[3]);
        nt_store4(out_f + base + 4, rv[4], rv[5], rv[6], rv[7]);
        uint4 o;
        o.x = pk_bf16(rv[0], rv[1]);
        o.y = pk_bf16(rv[2], rv[3]);
        o.z = pk_bf16(rv[4], rv[5]);
        o.w = pk_bf16(rv[6], rv[7]);
        *(uint4*)(out_bf + base) = o;   // re-read by GEMM2: keep cached
    }
}

// ---------------- agg2: narrow rows (FEAT=64), 8 nodes per wave ----------------
// Rows in t are PRE-SCALED by dinv[src]. R11 serial form, 4 edges in flight.
__global__ __launch_bounds__(256) void agg_n8_kernel(const u16* __restrict__ t,
                                                     const int* __restrict__ row_ptr,
                                                     const int* __restrict__ csr_src,
                                                     const float* __restrict__ dinv,
                                                     const float* __restrict__ bias,
                                                     float* __restrict__ out_f, int n) {
    constexpr int FEAT = 64;
    const int wid = (blockIdx.x * blockDim.x + threadIdx.x) >> 6;
    const int lane = threadIdx.x & 63;
    const int g = lane >> 3;   // node group 0..7
    const int r = lane & 7;    // lane within row
    const int node = wid * 8 + g;
    const bool valid = node < n;
    const int nd = valid ? node : (n - 1);
    const int beg = row_ptr[nd];
    const int deg = valid ? (row_ptr[nd + 1] - beg) : 0;

    // hoisted: self row, bias, dinv
    const float di = dinv[nd];
    uint4 sv = *(const uint4*)(t + (long)nd * FEAT + r * 8);
    float4 b0 = *(const float4*)(bias + r * 8);
    float4 b1 = *(const float4*)(bias + r * 8 + 4);

    float acc[8] = {};
    for (int e = 0;; e += 4) {
        if (!__any(e < deg)) break;
        int s[4]; float w[4]; uint4 v[4];
#pragma unroll
        for (int u = 0; u < 4; u++) {
            bool a = (e + u) < deg;
            s[u] = a ? csr_src[beg + e + u] : 0;
            w[u] = a ? 1.f : 0.f;
        }
#pragma unroll
        for (int u = 0; u < 4; u++) v[u] = *(const uint4*)(t + (long)s[u] * FEAT + r * 8);
#pragma unroll
        for (int u = 0; u < 4; u++) acc8(acc, v[u], w[u]);  // w=0 kills garbage rows
    }
    float self[8] = {bf_lo(sv.x), bf_hi(sv.x), bf_lo(sv.y), bf_hi(sv.y),
                     bf_lo(sv.z), bf_hi(sv.z), bf_lo(sv.w), bf_hi(sv.w)};
    float bb[8] = {b0.x, b0.y, b0.z, b0.w, b1.x, b1.y, b1.z, b1.w};
    float rv[8];
#pragma unroll
    for (int j = 0; j < 8; j++) {
        float v = di * (acc[j] + self[j]) + bb[j];
        // fast softplus: max(v,0) + ln(1+exp(-|v|)) via v_exp/v_log
        rv[j] = fmaxf(v, 0.f) + __logf(1.f + __expf(-fabsf(v)));
    }
    if (valid) {
        long base = (long)nd * FEAT + r * 8;
        nt_store4(out_f + base, rv[0], rv[1], rv[2], rv[3]);
        nt_store4(out_f + base + 4, rv[4], rv[5], rv[6], rv[7]);
    }
}

extern "C" void kernel_launch(void* const* d_in, const int* in_sizes, int n_in,
                              void* d_out, int out_size, void* d_ws, size_t ws_size,
                              hipStream_t stream) {
    const float* x  = (const float*)d_in[0];
    const int*   ei = (const int*)d_in[1];
    const float* W1 = (const float*)d_in[2];
    const float* b1 = (const float*)d_in[3];
    const float* W2 = (const float*)d_in[4];
    const float* b2 = (const float*)d_in[5];

    float* evidence = (float*)d_out;                        // [50000, 64]
    float* h        = (float*)d_out + (long)N_NODES * NCLS; // [50000, 256]

    const int E = in_sizes[1] / 2;
    const int* src = ei;
    const int* dst = ei + E;

    const int NB = (N_NODES + 255) / 256;  // 196 scan blocks

    // workspace carve-up (16B-aligned regions)
    char* w = (char*)d_ws;
    int*   cnt      = (int*)w;  w += 50048 * 4;
    int*   cursor   = (int*)w;  w += 50048 * 4;
    int*   row_ptr  = (int*)w;  w += 50064 * 4;
    float* dinv     = (float*)w; w += 50048 * 4;
    int*   blocksum = (int*)w;  w += 256 * 4;
    int*   csr_src  = (int*)w;  w += 800000 * 4;
    u16*   hbf      = (u16*)w;  w += (long)N_NODES * IN_DIM * 2;  // h bf16 (only HID used)
    u16*   w1t      = (u16*)w;  w += IN_DIM * HID * 2;
    u16*   w2t      = (u16*)w;  w += HID * NCLS * 2;
    u16*   t1bf     = (u16*)w;  w += (long)N_NODES * HID * 2;     // reused as t2_bf
    u16*   t2bf     = t1bf;

    // graph prep
    init_kernel<<<NB, 256, 0, stream>>>(cnt, cursor, N_NODES);
    count_kernel<<<(E + 255) / 256, 256, 0, stream>>>(dst, cnt, E);
    s1_kernel<<<NB, 256, 0, stream>>>(cnt, blocksum, dinv, N_NODES);
    s3_kernel<<<NB, 256, 0, stream>>>(cnt, blocksum, row_ptr, N_NODES, NB);
    fill_kernel<<<(E + 255) / 256, 256, 0, stream>>>(src, dst, row_ptr, cursor, csr_src, E);

    // weight casts (fused)
    {
        int tot = IN_DIM * HID + HID * NCLS;
        tcast2_kernel<<<(tot + 255) / 256, 256, 0, stream>>>(W1, w1t, W2, w2t);
    }

    // layer 1: t1 = dinv .* (x @ W1)  (fp32 A fused-cast, 2-deep prefetch);
    //          h = relu(dinv[d]*(sum t1[s] + t1[d]) + b1), also h_bf
    {
        dim3 grid(HID / 64, (N_NODES + 127) / 128);   // 4 x 391 = 1564 blocks
        mfma_gemm_kernel<128, 64, IN_DIM, HID, true, true>
            <<<grid, 256, 0, stream>>>(x, w1t, t1bf, N_NODES, dinv);
    }
    agg_wide_kernel<<<(N_NODES * 64 + 255) / 256, 256, 0, stream>>>(
        t1bf, row_ptr, csr_src, dinv, b1, h, hbf, N_NODES);

    // layer 2: t2 = dinv .* (h @ W2); evidence = softplus(dinv[d]*(sum+self) + b2)
    {
        dim3 grid(NCLS / 64, (N_NODES + 63) / 64);    // 1 x 782
        mfma_gemm_kernel<64, 64, HID, NCLS, false, true>
            <<<grid, 256, 0, stream>>>(hbf, w2t, t2bf, N_NODES, dinv);
    }
    {
        int waves = (N_NODES + 7) / 8;                 // 6250 waves
        int blocks = (waves + 3) / 4;                  // 4 waves per block
        agg_n8_kernel<<<blocks, 256, 0, stream>>>(
            t2bf, row_ptr, csr_src, dinv, b2, evidence, N_NODES);
    }
}

// Round 9
// 386.262 us; speedup vs baseline: 1.0917x; 1.0269x over previous
//
#include <hip/hip_runtime.h>

// EvidentialGNN: 2-layer GCN. evidence = softplus(gcn2(relu(gcn1(x)))).
// Outputs concatenated: (evidence[50000,64], h[50000,256]).
// R16 (= R15 resubmit; container infra failure last round): GEMM1 tile 64x256
//      (single column-tile, grid 1x782) so the 102MB fp32 x matrix is fetched
//      EXACTLY once. R14 counters showed FETCH=201MB = 2x A re-fetch with the
//      4-column-tile grid (B is 256KB, L2-resident, so per-block B re-staging
//      is free). 2-deep A prefetch + cvt_pk kept.

#define N_NODES 50000
#define IN_DIM 512
#define HID 256
#define NCLS 64

typedef unsigned short u16;
typedef unsigned int u32;
typedef __attribute__((ext_vector_type(8))) short short8;
typedef __attribute__((ext_vector_type(4))) float float4_t;

__device__ __forceinline__ float bf_lo(u32 v) {
    u32 u = v << 16; float f; __builtin_memcpy(&f, &u, 4); return f;
}
__device__ __forceinline__ float bf_hi(u32 v) {
    u32 u = v & 0xffff0000u; float f; __builtin_memcpy(&f, &u, 4); return f;
}
__device__ __forceinline__ u16 f2bf(float f) {   // RNE float->bf16
    u32 u; __builtin_memcpy(&u, &f, 4);
    return (u16)((u + 0x7fffu + ((u >> 16) & 1u)) >> 16);
}
__device__ __forceinline__ u32 pk_bf16(float lo, float hi) {  // HW RNE pack
    u32 r;
    asm("v_cvt_pk_bf16_f32 %0, %1, %2" : "=v"(r) : "v"(lo), "v"(hi));
    return r;
}
__device__ __forceinline__ void add8(float* acc, uint4 v) {
    acc[0] += bf_lo(v.x); acc[1] += bf_hi(v.x);
    acc[2] += bf_lo(v.y); acc[3] += bf_hi(v.y);
    acc[4] += bf_lo(v.z); acc[5] += bf_hi(v.z);
    acc[6] += bf_lo(v.w); acc[7] += bf_hi(v.w);
}
__device__ __forceinline__ void acc8(float* acc, uint4 v, float w) {
    acc[0] += w * bf_lo(v.x); acc[1] += w * bf_hi(v.x);
    acc[2] += w * bf_lo(v.y); acc[3] += w * bf_hi(v.y);
    acc[4] += w * bf_lo(v.z); acc[5] += w * bf_hi(v.z);
    acc[6] += w * bf_lo(v.w); acc[7] += w * bf_hi(v.w);
}
__device__ __forceinline__ void nt_store4(float* p, float a, float b, float c, float d) {
    float4_t v = {a, b, c, d};
    __builtin_nontemporal_store(v, (float4_t*)p);
}

// ---------------- graph prep ----------------
__global__ void init_kernel(int* __restrict__ cnt, int* __restrict__ cursor, int n) {
    int i = blockIdx.x * blockDim.x + threadIdx.x;
    if (i < n) { cnt[i] = 0; cursor[i] = 0; }
}

__global__ void count_kernel(const int* __restrict__ dst, int* __restrict__ cnt, int E) {
    int e = blockIdx.x * blockDim.x + threadIdx.x;
    if (e < E) atomicAdd(&cnt[dst[e]], 1);
}

// s1: per-block reduce of cnt -> blocksum; fused dinv = rsqrt(cnt+1).
__global__ __launch_bounds__(256) void s1_kernel(const int* __restrict__ cnt,
                                                 int* __restrict__ blocksum,
                                                 float* __restrict__ dinv, int n) {
    int tid = threadIdx.x;
    int i = blockIdx.x * 256 + tid;
    int c = (i < n) ? cnt[i] : 0;
    if (i < n) dinv[i] = rsqrtf((float)(c + 1));  // +1 self-loop
    __shared__ int s[256];
    s[tid] = c;
    __syncthreads();
    for (int off = 128; off > 0; off >>= 1) {
        if (tid < off) s[tid] += s[tid + off];
        __syncthreads();
    }
    if (tid == 0) blocksum[blockIdx.x] = s[0];
}

// s3 (fused s2): every block scans the <=256 block sums in LDS to get its own
// offset, then does the block-local exclusive scan -> row_ptr[0..n].
__global__ __launch_bounds__(256) void s3_kernel(const int* __restrict__ cnt,
                                                 const int* __restrict__ blocksum,
                                                 int* __restrict__ row_ptr, int n, int nb) {
    __shared__ int bs[256];
    __shared__ int s[256];
    int tid = threadIdx.x;
    int v = (tid < nb) ? blocksum[tid] : 0;
    bs[tid] = v;
    __syncthreads();
    for (int off = 1; off < 256; off <<= 1) {
        int a = (tid >= off) ? bs[tid - off] : 0;
        __syncthreads();
        bs[tid] += a;
        __syncthreads();
    }
    int boff = (blockIdx.x == 0) ? 0 : bs[blockIdx.x - 1];
    int i = blockIdx.x * 256 + tid;
    int c = (i < n) ? cnt[i] : 0;
    s[tid] = c;
    __syncthreads();
    for (int off = 1; off < 256; off <<= 1) {
        int a = (tid >= off) ? s[tid - off] : 0;
        __syncthreads();
        s[tid] += a;
        __syncthreads();
    }
    if (i <= n) row_ptr[i] = boff + s[tid] - c;
}

__global__ void fill_kernel(const int* __restrict__ src, const int* __restrict__ dst,
                            const int* __restrict__ row_ptr, int* __restrict__ cursor,
                            int* __restrict__ csr_src, int E) {
    int e = blockIdx.x * blockDim.x + threadIdx.x;
    if (e >= E) return;
    int d = dst[e];
    int pos = row_ptr[d] + atomicAdd(&cursor[d], 1);
    csr_src[pos] = src[e];
}

// ---------------- casts ----------------
// Both weight transposes in one launch.
__global__ __launch_bounds__(256) void tcast2_kernel(const float* __restrict__ W1,
                                                     u16* __restrict__ W1t,
                                                     const float* __restrict__ W2,
                                                     u16* __restrict__ W2t) {
    int idx = blockIdx.x * 256 + threadIdx.x;
    constexpr int N1 = IN_DIM * HID;
    if (idx < N1) {
        int n = idx / IN_DIM, k = idx - n * IN_DIM;
        W1t[idx] = f2bf(W1[k * HID + n]);
    } else {
        int j = idx - N1;
        if (j < HID * NCLS) {
            int n = j / HID, k = j - n * HID;
            W2t[j] = f2bf(W2[k * NCLS + n]);
        }
    }
}

// ---------------- bf16 MFMA GEMM (pipelined) ----------------
// C[M,N] = A[M,K] @ Bt[N,K]^T, fp32 accumulate, bf16 out.
// AF32: A fp32, staged via regs (2-deep prefetch: loadA(t+2) in flight while
// writeA(t+1) converts data issued a full iteration earlier -> wait ~free).
// SCALE: epilogue multiplies each output row by rowscale[row].
template <int BM, int BN, int K, int N, bool AF32, bool SCALE>
__global__ __launch_bounds__(256) void mfma_gemm_kernel(const void* __restrict__ Ain,
                                                        const u16* __restrict__ Bt,
                                                        u16* __restrict__ C, int M,
                                                        const float* __restrict__ rowscale) {
    constexpr int WROWS = 2, WCOLS = 2;
    constexpr int WMR = BM / WROWS;      // rows per wave
    constexpr int WNR = BN / WCOLS;      // cols per wave
    constexpr int MR = WMR / 16;         // A-frag repeat
    constexpr int NR = WNR / 16;         // B-frag repeat
    constexpr int AI = BM / 64;          // A staging iters
    constexpr int BI = BN / 64;          // B staging iters
    constexpr int LDSA = BM * 32;        // u16 per buffer
    constexpr int LDSB = BN * 32;
    constexpr int LDST = LDSA + LDSB;
    constexpr int NT = K / 32;
    static_assert(MR * 16 * WROWS == BM && NR * 16 * WCOLS == BN, "tiling");
    static_assert(!AF32 || (NT % 2 == 0), "2-deep prefetch needs even NT");
    __shared__ u16 lds[2 * LDST];

    const int tid = threadIdx.x;
    const int wave = tid >> 6, lane = tid & 63;
    const int wm = wave / WCOLS, wn = wave % WCOLS;
    const int quad = lane >> 4, l15 = lane & 15;
    const int row0 = blockIdx.y * BM;
    const int col0 = blockIdx.x * BN;

    const float* Af = (const float*)Ain;
    const u16* Abf = (const u16*)Ain;

    int gra[AI];
#pragma unroll
    for (int i = 0; i < AI; i++) {
        int gr = row0 + ((tid + i * 256) >> 2);
        gra[i] = gr < M ? gr : M - 1;
    }

    auto loadA = [&](int k0, float4 (&pa)[AI][2]) {
#pragma unroll
        for (int i = 0; i < AI; i++) {
            int c = tid + i * 256;
            const float* gp = Af + (long)gra[i] * K + k0 + (c & 3) * 8;
            pa[i][0] = ((const float4*)gp)[0];
            pa[i][1] = ((const float4*)gp)[1];
        }
    };
    auto writeA = [&](u16* buf, float4 (&pa)[AI][2]) {
#pragma unroll
        for (int i = 0; i < AI; i++) {
            int c = tid + i * 256;
            uint4 o;
            o.x = pk_bf16(pa[i][0].x, pa[i][0].y);
            o.y = pk_bf16(pa[i][0].z, pa[i][0].w);
            o.z = pk_bf16(pa[i][1].x, pa[i][1].y);
            o.w = pk_bf16(pa[i][1].z, pa[i][1].w);
            *(uint4*)(buf + c * 8) = o;
        }
    };
    auto stageA_lds = [&](int k0, u16* buf) {
#pragma unroll
        for (int i = 0; i < AI; i++) {
            int c = tid + i * 256;
            const u16* gp = Abf + (long)gra[i] * K + k0 + (c & 3) * 8;
            __builtin_amdgcn_global_load_lds((const __attribute__((address_space(1))) u32*)gp,
                                             (__attribute__((address_space(3))) u32*)(buf + c * 8),
                                             16, 0, 0);
        }
    };
    auto stageB = [&](int k0, u16* buf) {
#pragma unroll
        for (int i = 0; i < BI; i++) {
            int c = tid + i * 256;
            int r = c >> 2;
            const u16* gp = Bt + (long)(col0 + r) * K + k0 + (c & 3) * 8;
            __builtin_amdgcn_global_load_lds((const __attribute__((address_space(1))) u32*)gp,
                                             (__attribute__((address_space(3))) u32*)(buf + c * 8),
                                             16, 0, 0);
        }
    };

    float4_t acc[MR][NR];
#pragma unroll
    for (int mi = 0; mi < MR; mi++)
#pragma unroll
        for (int ni = 0; ni < NR; ni++) {
            float4_t z = {0.f, 0.f, 0.f, 0.f};
            acc[mi][ni] = z;
        }

    // per-iteration compute on buffer `cur`
    auto compute = [&](const u16* cur) {
        short8 af[MR], bfr[NR];
#pragma unroll
        for (int mi = 0; mi < MR; mi++)
            af[mi] = *(const short8*)(cur + (wm * WMR + mi * 16 + l15) * 32 + quad * 8);
#pragma unroll
        for (int ni = 0; ni < NR; ni++)
            bfr[ni] = *(const short8*)(cur + LDSA + (wn * WNR + ni * 16 + l15) * 32 + quad * 8);
#pragma unroll
        for (int mi = 0; mi < MR; mi++)
#pragma unroll
            for (int ni = 0; ni < NR; ni++)
                acc[mi][ni] = __builtin_amdgcn_mfma_f32_16x16x32_bf16(af[mi], bfr[ni],
                                                                      acc[mi][ni], 0, 0, 0);
    };

    if constexpr (AF32) {
        float4 paA[AI][2], paB[AI][2];   // named double prefetch buffers
        loadA(0, paA);
        writeA(lds, paA);                // tile 0 -> buf0
        stageB(0, lds + LDSA);
        loadA(32, paA);                  // tile 1 in flight
        __syncthreads();

        // unroll-by-2 so paA/paB stay statically named (no runtime indexing)
        for (int t = 0; t < NT; t += 2) {
            // even step: cur=buf[t&1]=buf0-parity; paA holds tile t+1
            {
                u16* cur = lds + (t & 1) * LDST;
                u16* nxt = lds + ((t + 1) & 1) * LDST;
                if (t + 2 < NT) loadA((t + 2) * 32, paB);
                if (t + 1 < NT) stageB((t + 1) * 32, nxt + LDSA);
                compute(cur);
                if (t + 1 < NT) writeA(nxt, paA);  // data issued 1 full iter ago
                __syncthreads();
            }
            // odd step: paB holds tile t+2
            {
                int t1 = t + 1;
                if (t1 < NT) {
                    u16* cur = lds + (t1 & 1) * LDST;
                    u16* nxt = lds + ((t1 + 1) & 1) * LDST;
                    if (t1 + 2 < NT) loadA((t1 + 2) * 32, paA);
                    if (t1 + 1 < NT) stageB((t1 + 1) * 32, nxt + LDSA);
                    compute(cur);
                    if (t1 + 1 < NT) writeA(nxt, paB);
                    __syncthreads();
                }
            }
        }
    } else {
        stageA_lds(0, lds);
        stageB(0, lds + LDSA);
        __syncthreads();
        for (int t = 0; t < NT; t++) {
            u16* cur = lds + (t & 1) * LDST;
            u16* nxt = lds + ((t + 1) & 1) * LDST;
            const bool pre = (t + 1) < NT;
            if (pre) {
                stageA_lds((t + 1) * 32, nxt);
                stageB((t + 1) * 32, nxt + LDSA);
            }
            compute(cur);
            __syncthreads();
        }
    }

#pragma unroll
    for (int mi = 0; mi < MR; mi++) {
#pragma unroll
        for (int r = 0; r < 4; r++) {
            int row = row0 + wm * WMR + mi * 16 + quad * 4 + r;
            if (row < M) {
                float sc = 1.f;
                if constexpr (SCALE) sc = rowscale[row];
#pragma unroll
                for (int ni = 0; ni < NR; ni++) {
                    int col = col0 + wn * WNR + ni * 16 + l15;
                    C[(long)row * N + col] = f2bf(acc[mi][ni][r] * sc);
                }
            }
        }
    }
}

// ---------------- agg1: wide rows (FEAT=256), one node per wave ----------------
// Rows in t are PRE-SCALED by dinv[src] (GEMM epilogue): pure row-sum.
// R11 serial-batch form (48 VGPR, 8 waves/SIMD tier) — per-wave ping-pong
// regressed occupancy (R12/R13).
__global__ __launch_bounds__(256) void agg_wide_kernel(const u16* __restrict__ t,
                                                       const int* __restrict__ row_ptr,
                                                       const int* __restrict__ csr_src,
                                                       const float* __restrict__ dinv,
                                                       const float* __restrict__ bias,
                                                       float* __restrict__ out_f,
                                                       u16* __restrict__ out_bf, int n) {
    constexpr int FEAT = 256;
    int node = (blockIdx.x * blockDim.x + threadIdx.x) >> 6;
    int lane = threadIdx.x & 63;
    if (node >= n) return;
    const int g = lane >> 5;       // edge group 0..1
    const int r = lane & 31;       // lane within row

    // hoisted: self row, bias, dinv (latency hidden under the edge loop)
    const float di = dinv[node];
    uint4 sv = *(const uint4*)(t + (long)node * FEAT + r * 8);
    float4 b0 = *(const float4*)(bias + r * 8);
    float4 b1 = *(const float4*)(bias + r * 8 + 4);

    float acc[8] = {};
    const int beg = row_ptr[node], end = row_ptr[node + 1];
    int e = beg;
    for (; e + 16 <= end; e += 16) {   // 8 edges per group, 16 chains in flight
        int s[8]; uint4 v[8];
#pragma unroll
        for (int u = 0; u < 8; u++) s[u] = csr_src[e + u * 2 + g];
#pragma unroll
        for (int u = 0; u < 8; u++) v[u] = *(const uint4*)(t + (long)s[u] * FEAT + r * 8);
#pragma unroll
        for (int u = 0; u < 8; u++) add8(acc, v[u]);
    }
    for (; e + 8 <= end; e += 8) {
        int s[4]; uint4 v[4];
#pragma unroll
        for (int u = 0; u < 4; u++) s[u] = csr_src[e + u * 2 + g];
#pragma unroll
        for (int u = 0; u < 4; u++) v[u] = *(const uint4*)(t + (long)s[u] * FEAT + r * 8);
#pragma unroll
        for (int u = 0; u < 4; u++) add8(acc, v[u]);
    }
    for (; e < end; e += 2) {
        int ee = e + g;
        if (ee < end) {
            int s = csr_src[ee];
            uint4 v = *(const uint4*)(t + (long)s * FEAT + r * 8);
            add8(acc, v);
        }
    }
#pragma unroll
    for (int j = 0; j < 8; j++) acc[j] += __shfl_xor(acc[j], 32, 64);

    if (lane < 32) {
        float self[8] = {bf_lo(sv.x), bf_hi(sv.x), bf_lo(sv.y), bf_hi(sv.y),
                         bf_lo(sv.z), bf_hi(sv.z), bf_lo(sv.w), bf_hi(sv.w)};
        float bb[8] = {b0.x, b0.y, b0.z, b0.w, b1.x, b1.y, b1.z, b1.w};
        float rv[8];
#pragma unroll
        for (int j = 0; j < 8; j++)
            rv[j] = fmaxf(di * (acc[j] + self[j]) + bb[j], 0.f);  // relu
        long base = (long)node * FEAT + lane * 8;
        nt_store4(out_f + base, rv[0], rv[1], rv[2], rv[3]);
        nt_store4(out_f + base + 4, rv[4], rv[5], rv[6], rv[7]);
        uint4 o;
        o.x = pk_bf16(rv[0], rv[1]);
        o.y = pk_bf16(rv[2], rv[3]);
        o.z = pk_bf16(rv[4], rv[5]);
        o.w = pk_bf16(rv[6], rv[7]);
        *(uint4*)(out_bf + base) = o;   // re-read by GEMM2: keep cached
    }
}

// ---------------- agg2: narrow rows (FEAT=64), 8 nodes per wave ----------------
// Rows in t are PRE-SCALED by dinv[src]. R11 serial form, 4 edges in flight.
__global__ __launch_bounds__(256) void agg_n8_kernel(const u16* __restrict__ t,
                                                     const int* __restrict__ row_ptr,
                                                     const int* __restrict__ csr_src,
                                                     const float* __restrict__ dinv,
                                                     const float* __restrict__ bias,
                                                     float* __restrict__ out_f, int n) {
    constexpr int FEAT = 64;
    const int wid = (blockIdx.x * blockDim.x + threadIdx.x) >> 6;
    const int lane = threadIdx.x & 63;
    const int g = lane >> 3;   // node group 0..7
    const int r = lane & 7;    // lane within row
    const int node = wid * 8 + g;
    const bool valid = node < n;
    const int nd = valid ? node : (n - 1);
    const int beg = row_ptr[nd];
    const int deg = valid ? (row_ptr[nd + 1] - beg) : 0;

    // hoisted: self row, bias, dinv
    const float di = dinv[nd];
    uint4 sv = *(const uint4*)(t + (long)nd * FEAT + r * 8);
    float4 b0 = *(const float4*)(bias + r * 8);
    float4 b1 = *(const float4*)(bias + r * 8 + 4);

    float acc[8] = {};
    for (int e = 0;; e += 4) {
        if (!__any(e < deg)) break;
        int s[4]; float w[4]; uint4 v[4];
#pragma unroll
        for (int u = 0; u < 4; u++) {
            bool a = (e + u) < deg;
            s[u] = a ? csr_src[beg + e + u] : 0;
            w[u] = a ? 1.f : 0.f;
        }
#pragma unroll
        for (int u = 0; u < 4; u++) v[u] = *(const uint4*)(t + (long)s[u] * FEAT + r * 8);
#pragma unroll
        for (int u = 0; u < 4; u++) acc8(acc, v[u], w[u]);  // w=0 kills garbage rows
    }
    float self[8] = {bf_lo(sv.x), bf_hi(sv.x), bf_lo(sv.y), bf_hi(sv.y),
                     bf_lo(sv.z), bf_hi(sv.z), bf_lo(sv.w), bf_hi(sv.w)};
    float bb[8] = {b0.x, b0.y, b0.z, b0.w, b1.x, b1.y, b1.z, b1.w};
    float rv[8];
#pragma unroll
    for (int j = 0; j < 8; j++) {
        float v = di * (acc[j] + self[j]) + bb[j];
        // fast softplus: max(v,0) + ln(1+exp(-|v|)) via v_exp/v_log
        rv[j] = fmaxf(v, 0.f) + __logf(1.f + __expf(-fabsf(v)));
    }
    if (valid) {
        long base = (long)nd * FEAT + r * 8;
        nt_store4(out_f + base, rv[0], rv[1], rv[2], rv[3]);
        nt_store4(out_f + base + 4, rv[4], rv[5], rv[6], rv[7]);
    }
}

extern "C" void kernel_launch(void* const* d_in, const int* in_sizes, int n_in,
                              void* d_out, int out_size, void* d_ws, size_t ws_size,
                              hipStream_t stream) {
    const float* x  = (const float*)d_in[0];
    const int*   ei = (const int*)d_in[1];
    const float* W1 = (const float*)d_in[2];
    const float* b1 = (const float*)d_in[3];
    const float* W2 = (const float*)d_in[4];
    const float* b2 = (const float*)d_in[5];

    float* evidence = (float*)d_out;                        // [50000, 64]
    float* h        = (float*)d_out + (long)N_NODES * NCLS; // [50000, 256]

    const int E = in_sizes[1] / 2;
    const int* src = ei;
    const int* dst = ei + E;

    const int NB = (N_NODES + 255) / 256;  // 196 scan blocks

    // workspace carve-up (16B-aligned regions)
    char* w = (char*)d_ws;
    int*   cnt      = (int*)w;  w += 50048 * 4;
    int*   cursor   = (int*)w;  w += 50048 * 4;
    int*   row_ptr  = (int*)w;  w += 50064 * 4;
    float* dinv     = (float*)w; w += 50048 * 4;
    int*   blocksum = (int*)w;  w += 256 * 4;
    int*   csr_src  = (int*)w;  w += 800000 * 4;
    u16*   hbf      = (u16*)w;  w += (long)N_NODES * IN_DIM * 2;  // h bf16 (only HID used)
    u16*   w1t      = (u16*)w;  w += IN_DIM * HID * 2;
    u16*   w2t      = (u16*)w;  w += HID * NCLS * 2;
    u16*   t1bf     = (u16*)w;  w += (long)N_NODES * HID * 2;     // reused as t2_bf
    u16*   t2bf     = t1bf;

    // graph prep
    init_kernel<<<NB, 256, 0, stream>>>(cnt, cursor, N_NODES);
    count_kernel<<<(E + 255) / 256, 256, 0, stream>>>(dst, cnt, E);
    s1_kernel<<<NB, 256, 0, stream>>>(cnt, blocksum, dinv, N_NODES);
    s3_kernel<<<NB, 256, 0, stream>>>(cnt, blocksum, row_ptr, N_NODES, NB);
    fill_kernel<<<(E + 255) / 256, 256, 0, stream>>>(src, dst, row_ptr, cursor, csr_src, E);

    // weight casts (fused)
    {
        int tot = IN_DIM * HID + HID * NCLS;
        tcast2_kernel<<<(tot + 255) / 256, 256, 0, stream>>>(W1, w1t, W2, w2t);
    }

    // layer 1: t1 = dinv .* (x @ W1)  (fp32 A fused-cast, 2-deep prefetch);
    //          h = relu(dinv[d]*(sum t1[s] + t1[d]) + b1), also h_bf
    //          BN=256: single column-tile -> x fetched exactly once (102MB).
    {
        dim3 grid(HID / 256, (N_NODES + 63) / 64);    // 1 x 782
        mfma_gemm_kernel<64, 256, IN_DIM, HID, true, true>
            <<<grid, 256, 0, stream>>>(x, w1t, t1bf, N_NODES, dinv);
    }
    agg_wide_kernel<<<(N_NODES * 64 + 255) / 256, 256, 0, stream>>>(
        t1bf, row_ptr, csr_src, dinv, b1, h, hbf, N_NODES);

    // layer 2: t2 = dinv .* (h @ W2); evidence = softplus(dinv[d]*(sum+self) + b2)
    {
        dim3 grid(NCLS / 64, (N_NODES + 63) / 64);    // 1 x 782
        mfma_gemm_kernel<64, 64, HID, NCLS, false, true>
            <<<grid, 256, 0, stream>>>(hbf, w2t, t2bf, N_NODES, dinv);
    }
    {
        int waves = (N_NODES + 7) / 8;                 // 6250 waves
        int blocks = (waves + 3) / 4;                  // 4 waves per block
        agg_n8_kernel<<<blocks, 256, 0, stream>>>(
            t2bf, row_ptr, csr_src, dinv, b2, evidence, N_NODES);
    }
}